// Round 9
// baseline (1262.126 us; speedup 1.0000x reference)
//
#include <hip/hip_runtime.h>
#include <math.h>

#define BB 16
#define TT 1024
#define T1 1025
#define DD 512
#define NSCAN 16
#define NALPHA 256
#define NBLK (NSCAN + NALPHA)
#define NJOBS (BB * T1)
#define DONEBIT 0x10000u

__device__ __forceinline__ float fract_exact(float x) {
#if defined(__has_builtin)
#if __has_builtin(__builtin_amdgcn_fractf)
    return __builtin_amdgcn_fractf(x);     // v_fract_f32: x - floor(x), exact
#else
    return x - floorf(x);
#endif
#else
    return x - floorf(x);
#endif
}

// ctrl layout (ints): acnt[16], progress[16], qhead[1]
__global__ void init_kernel(int* __restrict__ ctrl) {
    int i = threadIdx.x;
    if (i < 33) ctrl[i] = 0;
}

__global__ __launch_bounds__(256, 2) void cif_fused(
    const float* __restrict__ hidden,      // [B, T, D]
    const float* __restrict__ w,           // [D]
    const float* __restrict__ bias,        // [1]
    float* __restrict__ ae,                // [B, T1, D]
    float* __restrict__ token_num,         // [B]
    float* __restrict__ alphas_out,        // [B, T1]
    float* __restrict__ cif_peak,          // [B, T1]
    int*   __restrict__ fire_time,         // ws [B, T1]
    int*   __restrict__ ctrl)              // ws [33]
{
    int* acnt     = ctrl;
    int* progress = ctrl + 16;
    int* qhead    = ctrl + 32;

    int tid  = threadIdx.x;
    int wv   = tid >> 6;
    int lane = tid & 63;
    int blk  = blockIdx.x;

    __shared__ __align__(16) float a_sh[1120];   // alphas + zero pad (chain prefetch)
    __shared__ __align__(16) float p_sh[1026];   // peaks + tail

    if (blk >= NSCAN) {
        // ================= alpha producer: 64 rows per block =================
        int aid  = blk - NSCAN;              // 0..255
        int b    = aid >> 4;                 // 16 blocks per batch
        int base = aid * 64 + wv * 16;       // this wave's first global row
        float4 w0 = *(const float4*)(w + lane * 4);
        float4 w1 = *(const float4*)(w + 256 + lane * 4);
        float bz = bias[0];
        for (int i = 0; i < 16; i += 2) {    // 2-row unroll hides load latency
            int r0 = base + i;
            const float* h0 = hidden + (size_t)r0 * DD + lane * 4;
            const float* h1 = h0 + DD;
            float4 a0 = *(const float4*)h0;
            float4 a1 = *(const float4*)(h0 + 256);
            float4 b0 = *(const float4*)h1;
            float4 b1 = *(const float4*)(h1 + 256);
            float s0 = a0.x*w0.x + a0.y*w0.y + a0.z*w0.z + a0.w*w0.w
                     + a1.x*w1.x + a1.y*w1.y + a1.z*w1.z + a1.w*w1.w;
            float s1 = b0.x*w0.x + b0.y*w0.y + b0.z*w0.z + b0.w*w0.w
                     + b1.x*w1.x + b1.y*w1.y + b1.z*w1.z + b1.w*w1.w;
            #pragma unroll
            for (int off = 32; off > 0; off >>= 1) {
                s0 += __shfl_down(s0, off, 64);
                s1 += __shfl_down(s1, off, 64);
            }
            if (lane == 0) {
                alphas_out[b * T1 + (r0 & 1023)]       = 1.0f / (1.0f + expf(-(s0 + bz)));
                alphas_out[b * T1 + ((r0 + 1) & 1023)] = 1.0f / (1.0f + expf(-(s1 + bz)));
            }
        }
        __threadfence();                     // writes visible before counter bump
        __syncthreads();
        if (tid == 0) atomicAdd(&acnt[b], 1);
    } else {
        // ================= scan block for batch b =================
        int b = blk;
        if (tid == 0) {
            while (__hip_atomic_load(&acnt[b], __ATOMIC_ACQUIRE,
                                     __HIP_MEMORY_SCOPE_AGENT) < 16)
                __builtin_amdgcn_s_sleep(2);
        }
        __syncthreads();
        const float* src = alphas_out + b * T1;
        for (int t = tid; t < TT; t += 256)        a_sh[t] = src[t];
        for (int t = TT + tid; t < 1120; t += 256) a_sh[t] = 0.0f;
        if (tid == 0) alphas_out[b * T1 + TT] = 0.0f;   // tail column of alphas
        __syncthreads();

        float integrate = 0.0f;
        float4 c0, c1, c2, c3, c4, c5, c6, c7;
        float4 n0, n1, n2, n3, n4, n5, n6, n7;
        int cnt = 0;          // wave1: running fire count (lane-uniform)
        double tsum = 0.0;    // wave3: token_num partial

        if (tid == 0) {
            const float4* a4 = (const float4*)a_sh;
            c0 = a4[0]; c1 = a4[1]; c2 = a4[2]; c3 = a4[3];
            c4 = a4[4]; c5 = a4[5]; c6 = a4[6]; c7 = a4[7];
        }
        for (int c = 0; c < 16; ++c) {
            if (tid == 0) {
                int s = c * 64;
#define LD(OFF) (*(const float4*)(a_sh + (OFF)))
#define CH4(A, S) {                                                     \
                float4 P;                                               \
                float q0 = integrate + (A).x; P.x = q0; float j0 = fract_exact(q0); \
                float q1 = j0 + (A).y;        P.y = q1; float j1 = fract_exact(q1); \
                float q2 = j1 + (A).z;        P.z = q2; float j2 = fract_exact(q2); \
                float q3 = j2 + (A).w;        P.w = q3; integrate = fract_exact(q3); \
                *(float4*)(p_sh + (S)) = P; }
                // prefetch second half of this chunk
                n0 = LD(s + 32); n1 = LD(s + 36); n2 = LD(s + 40); n3 = LD(s + 44);
                n4 = LD(s + 48); n5 = LD(s + 52); n6 = LD(s + 56); n7 = LD(s + 60);
                // consume c-bank -> peaks s..s+31
                CH4(c0, s +  0) CH4(c1, s +  4) CH4(c2, s +  8) CH4(c3, s + 12)
                CH4(c4, s + 16) CH4(c5, s + 20) CH4(c6, s + 24) CH4(c7, s + 28)
                // prefetch first half of next chunk (zero pad keeps in-bounds)
                c0 = LD(s + 64); c1 = LD(s + 68); c2 = LD(s + 72); c3 = LD(s + 76);
                c4 = LD(s + 80); c5 = LD(s + 84); c6 = LD(s + 88); c7 = LD(s + 92);
                // consume n-bank -> peaks s+32..s+63
                CH4(n0, s + 32) CH4(n1, s + 36) CH4(n2, s + 40) CH4(n3, s + 44)
                CH4(n4, s + 48) CH4(n5, s + 52) CH4(n6, s + 56) CH4(n7, s + 60)
#undef CH4
#undef LD
                if (c == 15) p_sh[TT] = integrate;   // tail step (alpha=0, no fire)
            }
            __syncthreads();   // chunk c peaks ready in LDS
            if (wv == 1) {
                // incremental fire compaction for chunk c
                int t = c * 64 + lane;
                float p = p_sh[t];
                bool f = (p >= 1.0f);
                unsigned long long m = __ballot(f);
                int pos = cnt + __popcll(m & ((1ull << lane) - 1ull));
                if (f) fire_time[b * T1 + pos] = t;
                cnt += __popcll(m);
                __threadfence();
            } else if (wv == 2) {
                // coalesced peak writeout for chunk c
                int t = c * 64 + lane;
                cif_peak[b * T1 + t] = p_sh[t];
                if (c == 15 && lane == 0) cif_peak[b * T1 + TT] = p_sh[TT];
                __threadfence();
            } else if (wv == 3) {
                tsum += (double)a_sh[c * 64 + lane];
            }
            __syncthreads();   // fire/peak writes fenced by their producers
            if (tid == 64) {   // wave1 lane0 owns cnt -> publish progress
                unsigned pv = (c == 15) ? (DONEBIT | (unsigned)cnt) : (unsigned)cnt;
                __hip_atomic_store(&progress[b], (int)pv, __ATOMIC_RELEASE,
                                   __HIP_MEMORY_SCOPE_AGENT);
            }
        }
        if (wv == 3) {
            #pragma unroll
            for (int off = 32; off > 0; off >>= 1) tsum += __shfl_down(tsum, off, 64);
            if (lane == 0) token_num[b] = (float)floor(tsum);
        }
    }

    // ================= fill: wave-granular job queue =================
    for (;;) {
        int jv;
        if (lane == 0) jv = atomicAdd(qhead, 1);
        jv = __shfl(jv, 0, 64);
        if (jv >= NJOBS) break;
        int b = jv / T1;
        int j = jv - b * T1;
        unsigned p;
        for (;;) {
            p = (unsigned)__hip_atomic_load(&progress[b], __ATOMIC_ACQUIRE,
                                            __HIP_MEMORY_SCOPE_AGENT);
            if ((p & DONEBIT) || (p & 0xFFFFu) > (unsigned)j) break;
            __builtin_amdgcn_s_sleep(4);
        }
        float* out = ae + ((size_t)b * T1 + j) * DD + lane * 8;
        if ((p & DONEBIT) && (unsigned)j >= (p & 0xFFFFu)) {
            *(float4*)out       = make_float4(0.f, 0.f, 0.f, 0.f);
            *(float4*)(out + 4) = make_float4(0.f, 0.f, 0.f, 0.f);
            continue;
        }
        const int*   ft_b = fire_time + b * T1;
        const float* a_b  = alphas_out + b * T1;
        const float* pk_b = cif_peak + b * T1;
        const float* hb   = hidden + (size_t)b * TT * DD + lane * 8;
        int e = ft_b[j];
        float4 acc0 = make_float4(0.f, 0.f, 0.f, 0.f);
        float4 acc1 = make_float4(0.f, 0.f, 0.f, 0.f);
        int t0 = 0;
        if (j > 0) {
            int s = ft_b[j - 1];
            float ps   = (s > 0) ? pk_b[s - 1] : 0.0f;
            float ips  = (ps >= 1.0f) ? ps - 1.0f : ps;   // integrate before step s
            float r    = a_b[s] - (1.0f - ips);           // remainds at s (exact)
            const float* hr = hb + (size_t)s * DD;
            float4 h0 = *(const float4*)hr, h1 = *(const float4*)(hr + 4);
            acc0.x = r*h0.x; acc0.y = r*h0.y; acc0.z = r*h0.z; acc0.w = r*h0.w;
            acc1.x = r*h1.x; acc1.y = r*h1.y; acc1.z = r*h1.z; acc1.w = r*h1.w;
            t0 = s + 1;
        }
        for (int t = t0; t < e; ++t) {        // interior rows: cur = alpha
            float cc = a_b[t];
            const float* hr = hb + (size_t)t * DD;
            float4 h0 = *(const float4*)hr, h1 = *(const float4*)(hr + 4);
            acc0.x += cc*h0.x; acc0.y += cc*h0.y; acc0.z += cc*h0.z; acc0.w += cc*h0.w;
            acc1.x += cc*h1.x; acc1.y += cc*h1.y; acc1.z += cc*h1.z; acc1.w += cc*h1.w;
        }
        {   // final row t = e (the fire): cur = 1 - integrate_prev(e)
            float pe  = (e > 0) ? pk_b[e - 1] : 0.0f;
            float ipe = (pe >= 1.0f) ? pe - 1.0f : pe;
            float ce  = 1.0f - ipe;
            const float* hr = hb + (size_t)e * DD;
            float4 h0 = *(const float4*)hr, h1 = *(const float4*)(hr + 4);
            acc0.x += ce*h0.x; acc0.y += ce*h0.y; acc0.z += ce*h0.z; acc0.w += ce*h0.w;
            acc1.x += ce*h1.x; acc1.y += ce*h1.y; acc1.z += ce*h1.z; acc1.w += ce*h1.w;
        }
        *(float4*)out       = acc0;
        *(float4*)(out + 4) = acc1;
    }
}

extern "C" void kernel_launch(void* const* d_in, const int* in_sizes, int n_in,
                              void* d_out, int out_size, void* d_ws, size_t ws_size,
                              hipStream_t stream) {
    const float* hidden = (const float*)d_in[0];
    const float* w      = (const float*)d_in[1];
    const float* bias   = (const float*)d_in[2];

    float* out        = (float*)d_out;
    float* ae         = out;                                   // [B,T1,D]
    float* token_num  = out + (size_t)BB * T1 * DD;            // [B]
    float* alphas_out = token_num + BB;                        // [B,T1]
    float* cif_peak   = alphas_out + (size_t)BB * T1;          // [B,T1]

    int* fire_time = (int*)d_ws;                               // [B,T1]
    int* ctrl      = fire_time + (size_t)BB * T1;              // [33]

    init_kernel<<<1, 64, 0, stream>>>(ctrl);
    cif_fused<<<NBLK, 256, 0, stream>>>(hidden, w, bias,
                                        ae, token_num, alphas_out, cif_peak,
                                        fire_time, ctrl);
}

// Round 10
// 375.219 us; speedup vs baseline: 3.3637x; 3.3637x over previous
//
#include <hip/hip_runtime.h>
#include <math.h>

#define BB 16
#define TT 1024
#define T1 1025
#define DD 512
#define NSCAN 16
#define NALPHA 256
#define NBLK (NSCAN + NALPHA)
#define NJOBS (BB * T1)
#define NWF (NALPHA * 4 + NSCAN * 3)   // fill waves: 1024 alpha + 48 scan = 1072
#define DONEBIT 0x10000u

__device__ __forceinline__ float fract_exact(float x) {
#if defined(__has_builtin)
#if __has_builtin(__builtin_amdgcn_fractf)
    return __builtin_amdgcn_fractf(x);     // v_fract_f32: x - floor(x), exact
#else
    return x - floorf(x);
#endif
#else
    return x - floorf(x);
#endif
}

// ctrl layout (ints): acnt[16], progress[16]
__global__ void init_kernel(int* __restrict__ ctrl) {
    int i = threadIdx.x;
    if (i < 32) ctrl[i] = 0;
}

__global__ __launch_bounds__(256, 2) void cif_fused(
    const float* __restrict__ hidden,      // [B, T, D]
    const float* __restrict__ w,           // [D]
    const float* __restrict__ bias,        // [1]
    float* __restrict__ ae,                // [B, T1, D]
    float* __restrict__ token_num,         // [B]
    float* __restrict__ alphas_out,        // [B, T1]
    float* __restrict__ cif_peak,          // [B, T1]
    int*   __restrict__ fire_time,         // ws [B, T1]
    int*   __restrict__ ctrl)              // ws [32]
{
    int* acnt     = ctrl;
    int* progress = ctrl + 16;

    int tid  = threadIdx.x;
    int wv   = tid >> 6;
    int lane = tid & 63;
    int blk  = blockIdx.x;

    __shared__ __align__(16) float a_sh[1120];   // alphas + zero pad
    __shared__ __align__(16) float p_sh[1028];   // peaks + tail

    int fw = -1;   // fill wave id; -1 = no fill (chain wave)

    if (blk >= NSCAN) {
        // ================= alpha producer: 64 rows per block =================
        int aid  = blk - NSCAN;              // 0..255
        int b    = aid >> 4;                 // 16 blocks per batch
        int base = aid * 64 + wv * 16;       // this wave's first global row
        float4 w0 = *(const float4*)(w + lane * 4);
        float4 w1 = *(const float4*)(w + 256 + lane * 4);
        float bz = bias[0];
        for (int i = 0; i < 16; i += 2) {    // 2-row unroll hides load latency
            int r0 = base + i;
            const float* h0 = hidden + (size_t)r0 * DD + lane * 4;
            const float* h1 = h0 + DD;
            float4 a0 = *(const float4*)h0;
            float4 a1 = *(const float4*)(h0 + 256);
            float4 b0 = *(const float4*)h1;
            float4 b1 = *(const float4*)(h1 + 256);
            float s0 = a0.x*w0.x + a0.y*w0.y + a0.z*w0.z + a0.w*w0.w
                     + a1.x*w1.x + a1.y*w1.y + a1.z*w1.z + a1.w*w1.w;
            float s1 = b0.x*w0.x + b0.y*w0.y + b0.z*w0.z + b0.w*w0.w
                     + b1.x*w1.x + b1.y*w1.y + b1.z*w1.z + b1.w*w1.w;
            #pragma unroll
            for (int off = 32; off > 0; off >>= 1) {
                s0 += __shfl_down(s0, off, 64);
                s1 += __shfl_down(s1, off, 64);
            }
            if (lane == 0) {
                alphas_out[b * T1 + (r0 & 1023)]       = 1.0f / (1.0f + expf(-(s0 + bz)));
                alphas_out[b * T1 + ((r0 + 1) & 1023)] = 1.0f / (1.0f + expf(-(s1 + bz)));
            }
        }
        __threadfence();                     // writes visible before counter bump
        __syncthreads();
        if (tid == 0) atomicAdd(&acnt[b], 1);
        fw = aid * 4 + wv;                   // 0..1023
    } else {
        // ================= scan block for batch b =================
        int b = blk;
        if (tid == 0) {
            while (__hip_atomic_load(&acnt[b], __ATOMIC_ACQUIRE,
                                     __HIP_MEMORY_SCOPE_AGENT) < 16)
                __builtin_amdgcn_s_sleep(2);
        }
        __syncthreads();
        const float* src = alphas_out + b * T1;
        for (int t = tid; t < TT; t += 256)        a_sh[t] = src[t];
        for (int t = TT + tid; t < 1120; t += 256) a_sh[t] = 0.0f;
        if (tid == 0) alphas_out[b * T1 + TT] = 0.0f;   // tail column of alphas
        __syncthreads();
        // no more barriers below -> chain register banks never cross a barrier

        if (wv == 0) {
            // ---- chain wave: lane0 computes, all 64 lanes publish per chunk
            __builtin_amdgcn_s_setprio(1);
            float integrate = 0.0f;
            int cnt = 0;
            float4 c0, c1, c2, c3, c4, c5, c6, c7;
            float4 n0, n1, n2, n3, n4, n5, n6, n7;
            if (lane == 0) {
                const float4* a4 = (const float4*)a_sh;
                c0 = a4[0]; c1 = a4[1]; c2 = a4[2]; c3 = a4[3];
                c4 = a4[4]; c5 = a4[5]; c6 = a4[6]; c7 = a4[7];
            }
            for (int c = 0; c < 16; ++c) {
                if (lane == 0) {
                    int s = c * 64;
#define LD(OFF) (*(const float4*)(a_sh + (OFF)))
#define CH4(A, S) {                                                     \
                    float4 P;                                           \
                    float q0 = integrate + (A).x; P.x = q0; float j0 = fract_exact(q0); \
                    float q1 = j0 + (A).y;        P.y = q1; float j1 = fract_exact(q1); \
                    float q2 = j1 + (A).z;        P.z = q2; float j2 = fract_exact(q2); \
                    float q3 = j2 + (A).w;        P.w = q3; integrate = fract_exact(q3); \
                    *(float4*)(p_sh + (S)) = P; }
                    // prefetch second half of this chunk
                    n0 = LD(s + 32); n1 = LD(s + 36); n2 = LD(s + 40); n3 = LD(s + 44);
                    n4 = LD(s + 48); n5 = LD(s + 52); n6 = LD(s + 56); n7 = LD(s + 60);
                    // consume c-bank -> peaks s..s+31
                    CH4(c0, s +  0) CH4(c1, s +  4) CH4(c2, s +  8) CH4(c3, s + 12)
                    CH4(c4, s + 16) CH4(c5, s + 20) CH4(c6, s + 24) CH4(c7, s + 28)
                    // prefetch first half of next chunk (zero pad keeps in-bounds)
                    c0 = LD(s + 64); c1 = LD(s + 68); c2 = LD(s + 72); c3 = LD(s + 76);
                    c4 = LD(s + 80); c5 = LD(s + 84); c6 = LD(s + 88); c7 = LD(s + 92);
                    // consume n-bank -> peaks s+32..s+63
                    CH4(n0, s + 32) CH4(n1, s + 36) CH4(n2, s + 40) CH4(n3, s + 44)
                    CH4(n4, s + 48) CH4(n5, s + 52) CH4(n6, s + 56) CH4(n7, s + 60)
#undef CH4
#undef LD
                    if (c == 15) p_sh[TT] = integrate;   // tail step (alpha=0, no fire)
                }
                // same-wave LDS dependency: compiler orders via lgkmcnt
                int t = c * 64 + lane;
                float p = p_sh[t];
                cif_peak[b * T1 + t] = p;                // coalesced writeout
                if (c == 15 && lane == 0) cif_peak[b * T1 + TT] = p_sh[TT];
                bool f = (p >= 1.0f);
                unsigned long long m = __ballot(f);
                int pos = cnt + __popcll(m & ((1ull << lane) - 1ull));
                if (f) fire_time[b * T1 + pos] = t;
                cnt += __popcll(m);
                if (lane == 0) {                         // release orders prior stores
                    unsigned pv = (c == 15) ? (DONEBIT | (unsigned)cnt) : (unsigned)cnt;
                    __hip_atomic_store(&progress[b], (int)pv, __ATOMIC_RELEASE,
                                       __HIP_MEMORY_SCOPE_AGENT);
                }
            }
            __builtin_amdgcn_s_setprio(0);
            fw = -1;                                     // chain wave: no fill tail
        } else {
            if (wv == 1) {
                double s = 0.0;
                for (int t = lane; t < TT; t += 64) s += (double)a_sh[t];
                #pragma unroll
                for (int off = 32; off > 0; off >>= 1) s += __shfl_down(s, off, 64);
                if (lane == 0) token_num[b] = (float)floor(s);
            }
            fw = NALPHA * 4 + blk * 3 + (wv - 1);        // 1024..1071
        }
    }

    // ================= fill: static job partition (no atomics) =================
    if (fw < 0) return;
    for (int jv = fw; jv < NJOBS; jv += NWF) {
        int b = jv / T1;
        int j = jv - b * T1;
        unsigned p;
        for (;;) {
            p = (unsigned)__hip_atomic_load(&progress[b], __ATOMIC_ACQUIRE,
                                            __HIP_MEMORY_SCOPE_AGENT);
            if ((p & DONEBIT) || (p & 0xFFFFu) > (unsigned)j) break;
            __builtin_amdgcn_s_sleep(4);
        }
        float* out = ae + ((size_t)b * T1 + j) * DD + lane * 8;
        if ((p & DONEBIT) && (unsigned)j >= (p & 0xFFFFu)) {
            *(float4*)out       = make_float4(0.f, 0.f, 0.f, 0.f);
            *(float4*)(out + 4) = make_float4(0.f, 0.f, 0.f, 0.f);
            continue;
        }
        const int*   ft_b = fire_time + b * T1;
        const float* a_b  = alphas_out + b * T1;
        const float* pk_b = cif_peak + b * T1;
        const float* hb   = hidden + (size_t)b * TT * DD + lane * 8;
        int e = ft_b[j];
        float4 acc0 = make_float4(0.f, 0.f, 0.f, 0.f);
        float4 acc1 = make_float4(0.f, 0.f, 0.f, 0.f);
        int t0 = 0;
        if (j > 0) {
            int s = ft_b[j - 1];
            float ps   = (s > 0) ? pk_b[s - 1] : 0.0f;
            float ips  = (ps >= 1.0f) ? ps - 1.0f : ps;   // integrate before step s
            float r    = a_b[s] - (1.0f - ips);           // remainds at s (exact)
            const float* hr = hb + (size_t)s * DD;
            float4 h0 = *(const float4*)hr, h1 = *(const float4*)(hr + 4);
            acc0.x = r*h0.x; acc0.y = r*h0.y; acc0.z = r*h0.z; acc0.w = r*h0.w;
            acc1.x = r*h1.x; acc1.y = r*h1.y; acc1.z = r*h1.z; acc1.w = r*h1.w;
            t0 = s + 1;
        }
        for (int t = t0; t < e; ++t) {        // interior rows: cur = alpha
            float cc = a_b[t];
            const float* hr = hb + (size_t)t * DD;
            float4 h0 = *(const float4*)hr, h1 = *(const float4*)(hr + 4);
            acc0.x += cc*h0.x; acc0.y += cc*h0.y; acc0.z += cc*h0.z; acc0.w += cc*h0.w;
            acc1.x += cc*h1.x; acc1.y += cc*h1.y; acc1.z += cc*h1.z; acc1.w += cc*h1.w;
        }
        {   // final row t = e (the fire): cur = 1 - integrate_prev(e)
            float pe  = (e > 0) ? pk_b[e - 1] : 0.0f;
            float ipe = (pe >= 1.0f) ? pe - 1.0f : pe;
            float ce  = 1.0f - ipe;
            const float* hr = hb + (size_t)e * DD;
            float4 h0 = *(const float4*)hr, h1 = *(const float4*)(hr + 4);
            acc0.x += ce*h0.x; acc0.y += ce*h0.y; acc0.z += ce*h0.z; acc0.w += ce*h0.w;
            acc1.x += ce*h1.x; acc1.y += ce*h1.y; acc1.z += ce*h1.z; acc1.w += ce*h1.w;
        }
        *(float4*)out       = acc0;
        *(float4*)(out + 4) = acc1;
    }
}

extern "C" void kernel_launch(void* const* d_in, const int* in_sizes, int n_in,
                              void* d_out, int out_size, void* d_ws, size_t ws_size,
                              hipStream_t stream) {
    const float* hidden = (const float*)d_in[0];
    const float* w      = (const float*)d_in[1];
    const float* bias   = (const float*)d_in[2];

    float* out        = (float*)d_out;
    float* ae         = out;                                   // [B,T1,D]
    float* token_num  = out + (size_t)BB * T1 * DD;            // [B]
    float* alphas_out = token_num + BB;                        // [B,T1]
    float* cif_peak   = alphas_out + (size_t)BB * T1;          // [B,T1]

    int* fire_time = (int*)d_ws;                               // [B,T1]
    int* ctrl      = fire_time + (size_t)BB * T1;              // [32]

    init_kernel<<<1, 64, 0, stream>>>(ctrl);
    cif_fused<<<NBLK, 256, 0, stream>>>(hidden, w, bias,
                                        ae, token_num, alphas_out, cif_peak,
                                        fire_time, ctrl);
}

// Round 11
// 321.974 us; speedup vs baseline: 3.9200x; 1.1654x over previous
//
#include <hip/hip_runtime.h>
#include <math.h>

#define BB 16
#define TT 1024
#define T1 1025
#define DD 512
#define NSCAN 16
#define NALPHA 256
#define NBLK (NSCAN + NALPHA)
#define NJOBS (BB * T1)
#define NWF (NALPHA * 4 + NSCAN * 3)   // fill waves: 1024 alpha + 48 scan
#define CSTRIDE 16                     // ints per ctrl slot = 64B = own cacheline

__device__ __forceinline__ float fract_exact(float x) {
#if defined(__has_builtin)
#if __has_builtin(__builtin_amdgcn_fractf)
    return __builtin_amdgcn_fractf(x);     // v_fract_f32: x - floor(x), exact
#else
    return x - floorf(x);
#endif
#else
    return x - floorf(x);
#endif
}

// ctrl: acnt[b] = ctrl[b*CSTRIDE]; progress[b] = ctrl[(BB+b)*CSTRIDE]; 512 ints
__global__ void init_kernel(int* __restrict__ ctrl) {
    int i = threadIdx.x;
    if (i < 2 * BB * CSTRIDE) ctrl[i] = 0;
}

__global__ __launch_bounds__(256, 2) void cif_fused(
    const float* __restrict__ hidden,      // [B, T, D]
    const float* __restrict__ w,           // [D]
    const float* __restrict__ bias,        // [1]
    float* __restrict__ ae,                // [B, T1, D]
    float* __restrict__ token_num,         // [B]
    float* __restrict__ alphas_out,        // [B, T1]
    float* __restrict__ cif_peak,          // [B, T1]
    int*   __restrict__ fire_time,         // ws [B, T1]
    int*   __restrict__ ctrl)              // ws [512]
{
    int tid  = threadIdx.x;
    int wv   = tid >> 6;
    int lane = tid & 63;
    int blk  = blockIdx.x;

    __shared__ __align__(16) float a_sh[1120];   // alphas + zero pad
    __shared__ __align__(16) float p_sh[1028];   // peaks + tail
    __shared__ int chunk_flag;

    int fw = -1;   // fill wave id; -1 = chain wave (no fill tail)

    if (blk >= NSCAN) {
        // ================= alpha producer: 64 rows per block =================
        int aid  = blk - NSCAN;              // 0..255
        int b    = aid >> 4;                 // 16 blocks per batch
        int base = aid * 64 + wv * 16;       // this wave's first global row
        float4 w0 = *(const float4*)(w + lane * 4);
        float4 w1 = *(const float4*)(w + 256 + lane * 4);
        float bz = bias[0];
        for (int i = 0; i < 16; i += 2) {    // 2-row unroll hides load latency
            int r0 = base + i;
            const float* h0 = hidden + (size_t)r0 * DD + lane * 4;
            const float* h1 = h0 + DD;
            float4 a0 = *(const float4*)h0;
            float4 a1 = *(const float4*)(h0 + 256);
            float4 b0 = *(const float4*)h1;
            float4 b1 = *(const float4*)(h1 + 256);
            float s0 = a0.x*w0.x + a0.y*w0.y + a0.z*w0.z + a0.w*w0.w
                     + a1.x*w1.x + a1.y*w1.y + a1.z*w1.z + a1.w*w1.w;
            float s1 = b0.x*w0.x + b0.y*w0.y + b0.z*w0.z + b0.w*w0.w
                     + b1.x*w1.x + b1.y*w1.y + b1.z*w1.z + b1.w*w1.w;
            #pragma unroll
            for (int off = 32; off > 0; off >>= 1) {
                s0 += __shfl_down(s0, off, 64);
                s1 += __shfl_down(s1, off, 64);
            }
            if (lane == 0) {
                alphas_out[b * T1 + (r0 & 1023)]       = 1.0f / (1.0f + expf(-(s0 + bz)));
                alphas_out[b * T1 + ((r0 + 1) & 1023)] = 1.0f / (1.0f + expf(-(s1 + bz)));
            }
        }
        __threadfence();                     // writes visible before counter bump
        __syncthreads();
        if (tid == 0) atomicAdd(&ctrl[b * CSTRIDE], 1);
        fw = aid * 4 + wv;                   // 0..1023
    } else {
        // ================= scan block for batch b =================
        int b = blk;
        if (tid == 0) {
            while (__hip_atomic_load(&ctrl[b * CSTRIDE], __ATOMIC_ACQUIRE,
                                     __HIP_MEMORY_SCOPE_AGENT) < 16)
                __builtin_amdgcn_s_sleep(2);
            chunk_flag = 0;
        }
        __syncthreads();
        const float* src = alphas_out + b * T1;
        for (int t = tid; t < TT; t += 256)        a_sh[t] = src[t];
        for (int t = TT + tid; t < 1120; t += 256) a_sh[t] = 0.0f;
        if (tid == 0) alphas_out[b * T1 + TT] = 0.0f;   // tail column of alphas
        __syncthreads();
        // ---- no more barriers: roles below never re-converge ----

        if (wv == 0) {
            // chain wave: ENTIRE loop inside one divergent region -> no spill
            if (lane == 0) {
                __builtin_amdgcn_s_setprio(1);
                float integrate = 0.0f;
                float4 c0, c1, c2, c3, c4, c5, c6, c7;
                float4 n0, n1, n2, n3, n4, n5, n6, n7;
                const float4* a4 = (const float4*)a_sh;
                c0 = a4[0]; c1 = a4[1]; c2 = a4[2]; c3 = a4[3];
                c4 = a4[4]; c5 = a4[5]; c6 = a4[6]; c7 = a4[7];
                for (int c = 0; c < 16; ++c) {
                    int s = c * 64;
#define LD(OFF) (*(const float4*)(a_sh + (OFF)))
#define CH4(A, S) {                                                     \
                    float4 P;                                           \
                    float q0 = integrate + (A).x; P.x = q0; float j0 = fract_exact(q0); \
                    float q1 = j0 + (A).y;        P.y = q1; float j1 = fract_exact(q1); \
                    float q2 = j1 + (A).z;        P.z = q2; float j2 = fract_exact(q2); \
                    float q3 = j2 + (A).w;        P.w = q3; integrate = fract_exact(q3); \
                    *(float4*)(p_sh + (S)) = P; }
                    // prefetch second half of this chunk
                    n0 = LD(s + 32); n1 = LD(s + 36); n2 = LD(s + 40); n3 = LD(s + 44);
                    n4 = LD(s + 48); n5 = LD(s + 52); n6 = LD(s + 56); n7 = LD(s + 60);
                    // consume c-bank -> peaks s..s+31
                    CH4(c0, s +  0) CH4(c1, s +  4) CH4(c2, s +  8) CH4(c3, s + 12)
                    CH4(c4, s + 16) CH4(c5, s + 20) CH4(c6, s + 24) CH4(c7, s + 28)
                    // prefetch first half of next chunk (zero pad keeps in-bounds)
                    c0 = LD(s + 64); c1 = LD(s + 68); c2 = LD(s + 72); c3 = LD(s + 76);
                    c4 = LD(s + 80); c5 = LD(s + 84); c6 = LD(s + 88); c7 = LD(s + 92);
                    // consume n-bank -> peaks s+32..s+63
                    CH4(n0, s + 32) CH4(n1, s + 36) CH4(n2, s + 40) CH4(n3, s + 44)
                    CH4(n4, s + 48) CH4(n5, s + 52) CH4(n6, s + 56) CH4(n7, s + 60)
#undef CH4
#undef LD
                    if (c == 15) p_sh[TT] = integrate;   // tail step (alpha=0, no fire)
                    // workgroup-release: orders the ds_writes above before the flag
                    __hip_atomic_store(&chunk_flag, c + 1, __ATOMIC_RELEASE,
                                       __HIP_MEMORY_SCOPE_WORKGROUP);
                }
                __builtin_amdgcn_s_setprio(0);
            }
            return;   // chain wave (all 64 lanes) exits; no later barriers
        }
        if (wv == 1) {
            // publisher wave: per chunk -> peak writeout + compaction + progress
            int cnt = 0;
            int* prog = &ctrl[(BB + b) * CSTRIDE];
            for (int c = 0; c < 16; ++c) {
                while (__hip_atomic_load(&chunk_flag, __ATOMIC_ACQUIRE,
                                         __HIP_MEMORY_SCOPE_WORKGROUP) <= c)
                    __builtin_amdgcn_s_sleep(1);
                int t = c * 64 + lane;
                float p = p_sh[t];
                cif_peak[b * T1 + t] = p;                // coalesced writeout
                if (c == 15 && lane == 0) cif_peak[b * T1 + TT] = p_sh[TT];
                bool f = (p >= 1.0f);
                unsigned long long m = __ballot(f);
                int pos = cnt + __popcll(m & ((1ull << lane) - 1ull));
                if (f) fire_time[b * T1 + pos] = t;
                cnt += __popcll(m);
                __threadfence();                         // drain wave's stores
                if (lane == 0) {
                    int tdone = (c == 15) ? T1 : (c + 1) * 64;
                    __hip_atomic_store(prog, (tdone << 16) | cnt, __ATOMIC_RELEASE,
                                       __HIP_MEMORY_SCOPE_AGENT);
                }
            }
            fw = NALPHA * 4 + b * 3 + 0;
        } else if (wv == 2) {
            double s = 0.0;
            for (int t = lane; t < TT; t += 64) s += (double)a_sh[t];
            #pragma unroll
            for (int off = 32; off > 0; off >>= 1) s += __shfl_down(s, off, 64);
            if (lane == 0) token_num[b] = (float)floor(s);
            fw = NALPHA * 4 + b * 3 + 1;
        } else {
            fw = NALPHA * 4 + b * 3 + 2;
        }
    }

    // ================= fill: static job partition (no atomics) =================
    for (int jv = fw; jv < NJOBS; jv += NWF) {
        int b = jv / T1;
        int j = jv - b * T1;
        int* prog = &ctrl[(BB + b) * CSTRIDE];
        int cnt, tdone;
        for (;;) {
            int p = __hip_atomic_load(prog, __ATOMIC_ACQUIRE,
                                      __HIP_MEMORY_SCOPE_AGENT);
            cnt   = p & 0xFFFF;
            tdone = p >> 16;
            if (j < cnt) break;                       // segment fully defined
            if (j >= cnt + (T1 - tdone)) break;       // provably a zero row
            __builtin_amdgcn_s_sleep(4);
        }
        float* out = ae + ((size_t)b * T1 + j) * DD + lane * 8;
        if (j >= cnt) {                               // zero row (early or final)
            *(float4*)out       = make_float4(0.f, 0.f, 0.f, 0.f);
            *(float4*)(out + 4) = make_float4(0.f, 0.f, 0.f, 0.f);
            continue;
        }
        const int*   ft_b = fire_time + b * T1;
        const float* a_b  = alphas_out + b * T1;
        const float* pk_b = cif_peak + b * T1;
        const float* hb   = hidden + (size_t)b * TT * DD + lane * 8;
        int e = ft_b[j];
        float4 acc0 = make_float4(0.f, 0.f, 0.f, 0.f);
        float4 acc1 = make_float4(0.f, 0.f, 0.f, 0.f);
        int t0 = 0;
        if (j > 0) {
            int s = ft_b[j - 1];
            float ps   = (s > 0) ? pk_b[s - 1] : 0.0f;
            float ips  = (ps >= 1.0f) ? ps - 1.0f : ps;   // integrate before step s
            float r    = a_b[s] - (1.0f - ips);           // remainds at s (exact)
            const float* hr = hb + (size_t)s * DD;
            float4 h0 = *(const float4*)hr, h1 = *(const float4*)(hr + 4);
            acc0.x = r*h0.x; acc0.y = r*h0.y; acc0.z = r*h0.z; acc0.w = r*h0.w;
            acc1.x = r*h1.x; acc1.y = r*h1.y; acc1.z = r*h1.z; acc1.w = r*h1.w;
            t0 = s + 1;
        }
        for (int t = t0; t < e; ++t) {        // interior rows: cur = alpha
            float cc = a_b[t];
            const float* hr = hb + (size_t)t * DD;
            float4 h0 = *(const float4*)hr, h1 = *(const float4*)(hr + 4);
            acc0.x += cc*h0.x; acc0.y += cc*h0.y; acc0.z += cc*h0.z; acc0.w += cc*h0.w;
            acc1.x += cc*h1.x; acc1.y += cc*h1.y; acc1.z += cc*h1.z; acc1.w += cc*h1.w;
        }
        {   // final row t = e (the fire): cur = 1 - integrate_prev(e)
            float pe  = (e > 0) ? pk_b[e - 1] : 0.0f;
            float ipe = (pe >= 1.0f) ? pe - 1.0f : pe;
            float ce  = 1.0f - ipe;
            const float* hr = hb + (size_t)e * DD;
            float4 h0 = *(const float4*)hr, h1 = *(const float4*)(hr + 4);
            acc0.x += ce*h0.x; acc0.y += ce*h0.y; acc0.z += ce*h0.z; acc0.w += ce*h0.w;
            acc1.x += ce*h1.x; acc1.y += ce*h1.y; acc1.z += ce*h1.z; acc1.w += ce*h1.w;
        }
        *(float4*)out       = acc0;
        *(float4*)(out + 4) = acc1;
    }
}

extern "C" void kernel_launch(void* const* d_in, const int* in_sizes, int n_in,
                              void* d_out, int out_size, void* d_ws, size_t ws_size,
                              hipStream_t stream) {
    const float* hidden = (const float*)d_in[0];
    const float* w      = (const float*)d_in[1];
    const float* bias   = (const float*)d_in[2];

    float* out        = (float*)d_out;
    float* ae         = out;                                   // [B,T1,D]
    float* token_num  = out + (size_t)BB * T1 * DD;            // [B]
    float* alphas_out = token_num + BB;                        // [B,T1]
    float* cif_peak   = alphas_out + (size_t)BB * T1;          // [B,T1]

    int* fire_time = (int*)d_ws;                               // [B,T1]
    int* ctrl      = fire_time + (size_t)BB * T1;              // [512]

    init_kernel<<<1, 512, 0, stream>>>(ctrl);
    cif_fused<<<NBLK, 256, 0, stream>>>(hidden, w, bias,
                                        ae, token_num, alphas_out, cif_peak,
                                        fire_time, ctrl);
}

// Round 12
// 39.189 us; speedup vs baseline: 32.2064x; 8.2160x over previous
//
#include <hip/hip_runtime.h>
#include <math.h>

#define BB 16
#define TT 1024
#define T1 1025
#define DD 512

__device__ __forceinline__ float fract_exact(float x) {
#if defined(__has_builtin)
#if __has_builtin(__builtin_amdgcn_fractf)
    return __builtin_amdgcn_fractf(x);     // v_fract_f32: x - floor(x), exact
#else
    return x - floorf(x);
#endif
#else
    return x - floorf(x);
#endif
}

// ---------------- Kernel 1: alphas = sigmoid(hidden @ w + b) ----------------
// one 64-lane wave per (b,t) row; 4 waves per 256-thread block
__global__ __launch_bounds__(256) void alpha_kernel(
    const float* __restrict__ hidden,   // [B, T, D]
    const float* __restrict__ w,        // [D]
    const float* __restrict__ bias,     // [1]
    float* __restrict__ alphas_out)     // [B, T1]  (t < T written here)
{
    int row  = blockIdx.x * 4 + (threadIdx.x >> 6);   // 0 .. B*T-1
    int lane = threadIdx.x & 63;
    const float* h = hidden + (size_t)row * DD;
    float4 x0 = *(const float4*)(h + lane * 4);
    float4 x1 = *(const float4*)(h + 256 + lane * 4);
    float4 w0 = *(const float4*)(w + lane * 4);
    float4 w1 = *(const float4*)(w + 256 + lane * 4);
    float s = x0.x * w0.x + x0.y * w0.y + x0.z * w0.z + x0.w * w0.w
            + x1.x * w1.x + x1.y * w1.y + x1.z * w1.z + x1.w * w1.w;
    #pragma unroll
    for (int off = 32; off > 0; off >>= 1) s += __shfl_down(s, off, 64);
    if (lane == 0) {
        float x = s + bias[0];
        float sig = 1.0f / (1.0f + expf(-x));
        int b = row >> 10;       // / TT
        int t = row & 1023;      // % TT
        alphas_out[b * T1 + t] = sig;
    }
}

// ---------------- Kernel 2: sequential CIF scalar scan (per batch) ----------
// 128 threads. Wave0/lane0 runs the minimal serial chain:
//   ni = integrate + a;  peak[t] = ni;  integrate = fract(ni)   (bit-exact)
// 32-step chunks, 4-deep rotating register buffer (#pragma unroll 4 makes the
// rotation static -> zero v_movs; loads issued 128 steps ahead of use).
// Wave1 concurrently computes token_num. Then writeout + ballot compaction.
__global__ __launch_bounds__(128) void scan_kernel(
    float* __restrict__ alphas_out,   // [B, T1]; tail col written here
    float* __restrict__ token_num,    // [B]
    float* __restrict__ cif_peak,     // [B, T1]
    int*   __restrict__ fire_time,    // ws [B, T1]
    int*   __restrict__ nfired)       // ws [B]
{
    int b   = blockIdx.x;
    int tid = threadIdx.x;            // 0..127

    __shared__ float a_sh[TT + 128];  // 4 chunks of zero pad
    __shared__ float peak_sh[T1 + 3];

    // stage alphas (coalesced)
    for (int t = tid; t < TT; t += 128) a_sh[t] = alphas_out[b * T1 + t];
    for (int t = TT + tid; t < TT + 128; t += 128) a_sh[t] = 0.0f;
    __syncthreads();

    if (tid == 0) {
        const float4* a4 = (const float4*)a_sh;
        float4* p4 = (float4*)peak_sh;
        float integrate = 0.0f;

        float4 buf[4][8];             // 4-chunk rotation, 32 steps per chunk
        #pragma unroll
        for (int k = 0; k < 8; ++k) {
            buf[0][k] = a4[k];
            buf[1][k] = a4[8 + k];
            buf[2][k] = a4[16 + k];
            buf[3][k] = a4[24 + k];
        }

        #pragma unroll 4              // c&3 becomes static -> pure renaming
        for (int c = 0; c < 32; ++c) {
            float4 P[8];
            #pragma unroll
            for (int k = 0; k < 8; ++k) {
                float4 A = buf[c & 3][k];
                float n0 = integrate + A.x; P[k].x = n0; float i0 = fract_exact(n0);
                float n1 = i0 + A.y;        P[k].y = n1; float i1 = fract_exact(n1);
                float n2 = i1 + A.z;        P[k].z = n2; float i2 = fract_exact(n2);
                float n3 = i2 + A.w;        P[k].w = n3; integrate = fract_exact(n3);
            }
            #pragma unroll
            for (int k = 0; k < 8; ++k) p4[c * 8 + k] = P[k];
            #pragma unroll
            for (int k = 0; k < 8; ++k) buf[c & 3][k] = a4[(c + 4) * 8 + k]; // pad keeps in-bounds
        }
        // tail step: alpha = 0 -> ni == integrate (< 1, no fire)
        peak_sh[TT] = integrate;
    } else if (tid >= 64) {
        // ---- wave1: token_num = floor(sum alphas), concurrent with chain
        int lane = tid - 64;
        double s = 0.0;
        for (int t = lane; t < TT; t += 64) s += (double)a_sh[t];
        #pragma unroll
        for (int off = 32; off > 0; off >>= 1) s += __shfl_down(s, off, 64);
        if (lane == 0) {
            token_num[b] = (float)floor(s);
            alphas_out[b * T1 + TT] = 0.0f;       // tail column of alphas output
        }
    }
    __syncthreads();

    // coalesced writeout of peaks
    for (int t = tid; t < T1; t += 128) cif_peak[b * T1 + t] = peak_sh[t];

    // fire-time compaction on wave0: fire flag == (peak >= 1.0f)
    if (tid < 64) {
        int cnt = 0;
        int* ft_b = fire_time + b * T1;
        for (int base = 0; base < T1; base += 64) {
            int t = base + tid;
            bool f = (t < T1) && (peak_sh[t] >= 1.0f);
            unsigned long long m = __ballot(f);
            int pos = cnt + __popcll(m & ((1ull << tid) - 1ull));
            if (f) ft_b[pos] = t;
            cnt += __popcll(m);
        }
        if (tid == 0) nfired[b] = cnt;
    }
}

// ---------------- Kernel 3: segmented weighted sums -> packed frames --------
// ONE WAVE (64 threads) per output row; 8 floats per lane.
// cur/rem reconstructed exactly from (peak, alpha):
//   integrate_prev(t) = peak[t-1] >= 1 ? peak[t-1]-1 : peak[t-1]   (exact)
//   cur(fire t)       = 1 - integrate_prev(t)
//   interior cur(t)   = alpha[t]
//   rem(s)            = alpha[s] - cur(s)
__global__ __launch_bounds__(64) void fill_kernel(
    const float* __restrict__ hidden,     // [B, T, D]
    const float* __restrict__ alphas,     // [B, T1]
    const float* __restrict__ peak,       // [B, T1]
    const int*   __restrict__ fire_time,  // ws [B, T1]
    const int*   __restrict__ nfired,     // ws [B]
    float* __restrict__ ae)               // [B, T1, D]
{
    int idx  = blockIdx.x;
    int b    = idx / T1;
    int j    = idx - b * T1;
    int lane = threadIdx.x;
    float* out = ae + ((size_t)b * T1 + j) * DD + lane * 8;

    int nf = nfired[b];
    if (j >= nf) {                        // unfired slot: zeros
        *(float4*)out       = make_float4(0.f, 0.f, 0.f, 0.f);
        *(float4*)(out + 4) = make_float4(0.f, 0.f, 0.f, 0.f);
        return;
    }
    const int*   ft_b = fire_time + b * T1;
    const float* a_b  = alphas + b * T1;
    const float* pk_b = peak + b * T1;
    const float* hb   = hidden + (size_t)b * TT * DD + lane * 8;

    int e = ft_b[j];                      // fire time of this token
    float4 acc0 = make_float4(0.f, 0.f, 0.f, 0.f);
    float4 acc1 = make_float4(0.f, 0.f, 0.f, 0.f);
    int t0 = 0;
    if (j > 0) {
        int s = ft_b[j - 1];              // previous fire time
        float ps   = (s > 0) ? pk_b[s - 1] : 0.0f;
        float ips  = (ps >= 1.0f) ? ps - 1.0f : ps;   // integrate before step s
        float r    = a_b[s] - (1.0f - ips);           // remainds at s (exact)
        const float* hr = hb + (size_t)s * DD;
        float4 h0 = *(const float4*)hr, h1 = *(const float4*)(hr + 4);
        acc0.x = r*h0.x; acc0.y = r*h0.y; acc0.z = r*h0.z; acc0.w = r*h0.w;
        acc1.x = r*h1.x; acc1.y = r*h1.y; acc1.z = r*h1.z; acc1.w = r*h1.w;
        t0 = s + 1;
    }
    for (int t = t0; t < e; ++t) {        // interior rows: cur = alpha
        float cc = a_b[t];
        const float* hr = hb + (size_t)t * DD;
        float4 h0 = *(const float4*)hr, h1 = *(const float4*)(hr + 4);
        acc0.x += cc*h0.x; acc0.y += cc*h0.y; acc0.z += cc*h0.z; acc0.w += cc*h0.w;
        acc1.x += cc*h1.x; acc1.y += cc*h1.y; acc1.z += cc*h1.z; acc1.w += cc*h1.w;
    }
    {   // final row t = e (the fire): cur = 1 - integrate_prev(e)
        float pe  = (e > 0) ? pk_b[e - 1] : 0.0f;
        float ipe = (pe >= 1.0f) ? pe - 1.0f : pe;
        float ce  = 1.0f - ipe;
        const float* hr = hb + (size_t)e * DD;
        float4 h0 = *(const float4*)hr, h1 = *(const float4*)(hr + 4);
        acc0.x += ce*h0.x; acc0.y += ce*h0.y; acc0.z += ce*h0.z; acc0.w += ce*h0.w;
        acc1.x += ce*h1.x; acc1.y += ce*h1.y; acc1.z += ce*h1.z; acc1.w += ce*h1.w;
    }
    *(float4*)out       = acc0;
    *(float4*)(out + 4) = acc1;
}

extern "C" void kernel_launch(void* const* d_in, const int* in_sizes, int n_in,
                              void* d_out, int out_size, void* d_ws, size_t ws_size,
                              hipStream_t stream) {
    const float* hidden = (const float*)d_in[0];
    const float* w      = (const float*)d_in[1];
    const float* bias   = (const float*)d_in[2];

    float* out        = (float*)d_out;
    float* ae         = out;                                   // [B,T1,D]
    float* token_num  = out + (size_t)BB * T1 * DD;            // [B]
    float* alphas_out = token_num + BB;                        // [B,T1]
    float* cif_peak   = alphas_out + (size_t)BB * T1;          // [B,T1]

    int* fire_time = (int*)d_ws;                               // [B,T1]
    int* nfired    = fire_time + (size_t)BB * T1;              // [B]

    alpha_kernel<<<(BB * TT) / 4, 256, 0, stream>>>(hidden, w, bias, alphas_out);
    scan_kernel<<<BB, 128, 0, stream>>>(alphas_out, token_num, cif_peak,
                                        fire_time, nfired);
    fill_kernel<<<BB * T1, 64, 0, stream>>>(hidden, alphas_out, cif_peak,
                                            fire_time, nfired, ae);
}